// Round 1
// baseline (706.658 us; speedup 1.0000x reference)
//
#include <hip/hip_runtime.h>

// Conv2d via im2col == GEMM: Y[o, w] = sum_k X[w,k] * W[o,k] + b[o]
// O=512, K=49, Wn=262144. Output packed [O*Wn] fp32.
//
// Round 3: kill the LDS-broadcast bottleneck.
//  R2 was LDS-return-bandwidth bound (~832 ds_read_b128/wave x 128 waves/CU
//  x ~8cyc ~= 355us/CU >> 84us FMA floor): every lane redundantly received
//  the same broadcast weights, 4 FMA per ds_read_b128.
//  - 4 CONSECUTIVE windows per thread: each weight float4 now feeds 16 FMAs,
//    cutting LDS instructions 4x (-> ~89us, parity with the VALU floor).
//  - Consecutive windows make the per-thread x span 196 contiguous floats
//    (784 B, 16B-aligned) -> 49 float4 loads instead of 49 scalar gathers.
//  - Stores become float4: wave writes 1KB contiguous per channel.
//  - ~240 VGPR -> 2 waves/SIMD; __launch_bounds__(256,2) pins the 256-VGPR
//    cap so we don't fall off the occupancy cliff. 8-16 independent FMA
//    chains keep the VALU saturated at this occupancy.

#define KK 49
#define KP 52   // padded channel stride in LDS floats: 52*4 B = 208 B, 16B-aligned
#define OPC 64  // output channels per block
#define WPT 4   // consecutive windows per thread

__global__ __launch_bounds__(256, 2) void conv_im2col_kernel(
    const float* __restrict__ x,    // [Wn, 49]
    const float* __restrict__ wgt,  // [O, 49]
    const float* __restrict__ bias, // [O]
    float* __restrict__ out,        // [O, Wn] flattened
    int windows, int ochannels)
{
    __shared__ __align__(16) float ws[OPC][KP];
    __shared__ float bs[OPC];

    const int tid   = threadIdx.x;
    const int obase = blockIdx.y * OPC;

    // Stage this group's weights + bias into LDS (once per block).
    for (int idx = tid; idx < OPC * KK; idx += 256) {
        int ch = idx / KK;
        int k  = idx - ch * KK;
        ws[ch][k] = wgt[(size_t)(obase + ch) * KK + k];
    }
    if (tid < OPC) bs[tid] = bias[obase + tid];
    __syncthreads();

    const int w0 = (blockIdx.x * 256 + tid) * WPT;
    if (w0 >= windows) return;

    // 4 windows' im2col rows = 196 consecutive floats, 16B-aligned
    // (784 = 49*16). Load as 49 float4s into registers.
    float xf[WPT * KK];
    {
        const float4* xp = (const float4*)(x + (size_t)w0 * KK);
#pragma unroll
        for (int j = 0; j < KK; ++j) {
            float4 t = xp[j];
            xf[4 * j + 0] = t.x;
            xf[4 * j + 1] = t.y;
            xf[4 * j + 2] = t.z;
            xf[4 * j + 3] = t.w;
        }
    }

    for (int og = 0; og < OPC; og += 4) {
        float acc[4][WPT];  // [channel][window]
#pragma unroll
        for (int c = 0; c < 4; ++c) {
            float b = bs[og + c];
#pragma unroll
            for (int v = 0; v < WPT; ++v) acc[c][v] = b;
        }

#pragma unroll
        for (int k = 0; k < 48; k += 4) {
            float4 wq[4];
#pragma unroll
            for (int c = 0; c < 4; ++c)
                wq[c] = *(const float4*)&ws[og + c][k];
#pragma unroll
            for (int c = 0; c < 4; ++c) {
                const float wv[4] = {wq[c].x, wq[c].y, wq[c].z, wq[c].w};
#pragma unroll
                for (int kk = 0; kk < 4; ++kk) {
#pragma unroll
                    for (int v = 0; v < WPT; ++v)
                        acc[c][v] = fmaf(xf[v * KK + k + kk], wv[kk], acc[c][v]);
                }
            }
        }
        // k = 48 tail
#pragma unroll
        for (int c = 0; c < 4; ++c) {
            float wlast = ws[og + c][48];
#pragma unroll
            for (int v = 0; v < WPT; ++v)
                acc[c][v] = fmaf(xf[v * KK + 48], wlast, acc[c][v]);
        }

        // Store: 4 consecutive outputs per channel -> one float4 each.
        // w0 % 4 == 0 and windows % 4 == 0 -> 16B-aligned.
#pragma unroll
        for (int c = 0; c < 4; ++c) {
            float4 o4 = make_float4(acc[c][0], acc[c][1], acc[c][2], acc[c][3]);
            *(float4*)&out[(size_t)(obase + og + c) * windows + w0] = o4;
        }
    }
}

extern "C" void kernel_launch(void* const* d_in, const int* in_sizes, int n_in,
                              void* d_out, int out_size, void* d_ws, size_t ws_size,
                              hipStream_t stream) {
    const float* x    = (const float*)d_in[0];  // enc_x [Wn*49]
    const float* wgt  = (const float*)d_in[1];  // weight [O*49]
    const float* bias = (const float*)d_in[2];  // bias [O]

    const int windows   = in_sizes[0] / KK;  // 262144
    const int ochannels = in_sizes[1] / KK;  // 512

    float* out = (float*)d_out;

    dim3 block(256);
    dim3 grid((windows + 256 * WPT - 1) / (256 * WPT), ochannels / OPC);
    conv_im2col_kernel<<<grid, block, 0, stream>>>(x, wgt, bias, out,
                                                   windows, ochannels);
}

// Round 3
// 677.887 us; speedup vs baseline: 1.0424x; 1.0424x over previous
//
#include <hip/hip_runtime.h>

// Conv2d via im2col == GEMM: Y[o, w] = sum_k X[w,k] * W[o,k] + b[o]
// O=512, K=49, Wn=262144. Output packed [O*Wn] fp32.
//
// Round 5: resubmit of R4 (infra failure: container died before bench) with
// hardened types.
//  - fp32 VALU floor (84us) > memory floor (~93us) -> fp32 can never win;
//    regime change to MFMA via exact bf16 split:
//    x.w = (xh+xl).(wh+wl), all 4 products via mfma_f32_16x16x32_bf16.
//    Residual ~1e-3 << passing absmax 0.125. Compute ~34us, LDS ~65us,
//    HBM ~93us -> memory-bound target.
//  - Fragments typed as ext_vector_type(8) short (guide-verified compile
//    form on gfx950); fp32->bf16 split via explicit RNE bit ops, no __bf16.
//  - Block = 128 windows x 64 channels, 4 waves; wave = 32 windows.
//  - K=49 zero-padded to 64 on the weight side (LDS pad), A-tail zeroed.
//  - Xs[128][49] fp32 unpadded = linear image of the global block ->
//    staging is a pure float4 copy. Odd row stride (49 floats) spreads the
//    A-fragment ds_read_b32 across banks (2-way uniform = free, m136).
//  - Weights split to bf16 hi/lo in LDS, 72-elem row stride (144 B) for
//    16B-aligned ds_read_b128 B-fragments.
//  - D layout (m89): col=lane&15 (channel), row=(lane>>4)*4+reg (window)
//    -> 4 acc regs = 4 consecutive windows = one float4 store.

#define KK 49
#define BM 128      // windows per block
#define BN 64       // channels per block
#define WSTRIDE 72  // padded bf16 row stride for weights (144 B)

typedef short sh8  __attribute__((ext_vector_type(8)));   // 8 bf16 bit-patterns
typedef float f32x4 __attribute__((ext_vector_type(4)));

__device__ __forceinline__ unsigned short f2bf(float f) {
    union { float f; unsigned u; } v; v.f = f;
    unsigned u = v.u;
    return (unsigned short)((u + 0x7fffu + ((u >> 16) & 1u)) >> 16);  // RNE
}
__device__ __forceinline__ float bf2f(unsigned short h) {
    union { unsigned u; float f; } v; v.u = ((unsigned)h) << 16;
    return v.f;
}

__global__ __launch_bounds__(256) void conv_mfma_kernel(
    const float* __restrict__ x,    // [Wn, 49]
    const float* __restrict__ wgt,  // [O, 49]
    const float* __restrict__ bias, // [O]
    float* __restrict__ out,        // [O, Wn] flattened
    int windows)
{
    __shared__ __align__(16) float          Xs[BM * KK];       // 25088 B
    __shared__ __align__(16) unsigned short Wh[BN * WSTRIDE];  // 9216 B
    __shared__ __align__(16) unsigned short Wl[BN * WSTRIDE];  // 9216 B
    __shared__ float bs[BN];

    const int tid   = threadIdx.x;
    const int w0    = blockIdx.x * BM;
    const int obase = blockIdx.y * BN;

    // ---- stage weights: split fp32 -> bf16 hi + lo -------------------------
    for (int idx = tid; idx < BN * KK; idx += 256) {
        int ch = idx / KK;
        int k  = idx - ch * KK;
        float w = wgt[(size_t)(obase + ch) * KK + k];
        unsigned short hi = f2bf(w);
        unsigned short lo = f2bf(w - bf2f(hi));
        Wh[ch * WSTRIDE + k] = hi;
        Wl[ch * WSTRIDE + k] = lo;
    }
    // zero-pad k = 49..71 so the k>=49 fragment elements contribute exactly 0
    for (int idx = tid; idx < BN * (WSTRIDE - KK); idx += 256) {
        int ch = idx / (WSTRIDE - KK);
        int k  = KK + (idx - ch * (WSTRIDE - KK));
        Wh[ch * WSTRIDE + k] = 0;
        Wl[ch * WSTRIDE + k] = 0;
    }
    if (tid < BN) bs[tid] = bias[obase + tid];

    // ---- stage X: 128*49 = 6272 floats = 1568 float4, straight linear copy -
    {
        const float4* src = (const float4*)(x + (size_t)w0 * KK);
        float4* dst = (float4*)Xs;
#pragma unroll
        for (int it = 0; it < 6; ++it)
            dst[tid + it * 256] = src[tid + it * 256];
        if (tid < 1568 - 6 * 256)   // 32 remaining float4s
            dst[tid + 6 * 256] = src[tid + 6 * 256];
    }
    __syncthreads();

    const int wave = tid >> 6;
    const int lane = tid & 63;
    const int r = lane & 15;   // A: window-in-tile / B: channel / D: channel
    const int g = lane >> 4;   // k-group

    const int mbase = wave * 32;   // this wave's 32 windows (2 m-tiles)

    // ---- build A fragments in registers: bf16 split of X, K padded to 64 ---
    // A layout (16x16x32): row = lane&15, k = (lane>>4)*8 + j
    sh8 AH[2][2], AL[2][2];        // [mtile][kstep]
#pragma unroll
    for (int mt = 0; mt < 2; ++mt) {
        const float* xrow = &Xs[(mbase + mt * 16 + r) * KK];
#pragma unroll
        for (int s = 0; s < 2; ++s) {
#pragma unroll
            for (int j = 0; j < 8; ++j) {
                int k  = s * 32 + g * 8 + j;
                int kc = (k < KK) ? k : 0;       // clamp addr in-bounds
                float f = xrow[kc];
                f = (k < KK) ? f : 0.0f;         // zero the pad lanes
                unsigned short hi = f2bf(f);
                unsigned short lo = f2bf(f - bf2f(hi));
                AH[mt][s][j] = (short)hi;
                AL[mt][s][j] = (short)lo;
            }
        }
    }

    // ---- accumulators, bias-initialized (bias depends on channel = col) ----
    f32x4 acc[2][4];               // [mtile][ntile]
#pragma unroll
    for (int nt = 0; nt < 4; ++nt) {
        float b = bs[nt * 16 + r];
        f32x4 bi = {b, b, b, b};
        acc[0][nt] = bi;
        acc[1][nt] = bi;
    }

    // ---- main MFMA: 4 n-tiles x 2 m-tiles x 8 mfma (4 split-products x 2 k)
    // B layout (16x16x32): col = lane&15, k = (lane>>4)*8 + j
#pragma unroll
    for (int nt = 0; nt < 4; ++nt) {
        const int ch = nt * 16 + r;
        sh8 BH0 = *(const sh8*)&Wh[ch * WSTRIDE + g * 8];
        sh8 BH1 = *(const sh8*)&Wh[ch * WSTRIDE + 32 + g * 8];
        sh8 BL0 = *(const sh8*)&Wl[ch * WSTRIDE + g * 8];
        sh8 BL1 = *(const sh8*)&Wl[ch * WSTRIDE + 32 + g * 8];
#pragma unroll
        for (int mt = 0; mt < 2; ++mt) {
            f32x4 a = acc[mt][nt];
            a = __builtin_amdgcn_mfma_f32_16x16x32_bf16(AH[mt][0], BH0, a, 0, 0, 0);
            a = __builtin_amdgcn_mfma_f32_16x16x32_bf16(AL[mt][0], BH0, a, 0, 0, 0);
            a = __builtin_amdgcn_mfma_f32_16x16x32_bf16(AH[mt][0], BL0, a, 0, 0, 0);
            a = __builtin_amdgcn_mfma_f32_16x16x32_bf16(AL[mt][0], BL0, a, 0, 0, 0);
            a = __builtin_amdgcn_mfma_f32_16x16x32_bf16(AH[mt][1], BH1, a, 0, 0, 0);
            a = __builtin_amdgcn_mfma_f32_16x16x32_bf16(AL[mt][1], BH1, a, 0, 0, 0);
            a = __builtin_amdgcn_mfma_f32_16x16x32_bf16(AH[mt][1], BL1, a, 0, 0, 0);
            a = __builtin_amdgcn_mfma_f32_16x16x32_bf16(AL[mt][1], BL1, a, 0, 0, 0);
            acc[mt][nt] = a;
        }
    }

    // ---- store: D reg i -> window mbase+mt*16+g*4+i (4 consecutive) --------
#pragma unroll
    for (int mt = 0; mt < 2; ++mt) {
#pragma unroll
        for (int nt = 0; nt < 4; ++nt) {
            size_t o = (size_t)(obase + nt * 16 + r) * (size_t)windows
                     + (size_t)(w0 + mbase + mt * 16 + g * 4);
            *(f32x4*)&out[o] = acc[mt][nt];
        }
    }
}

extern "C" void kernel_launch(void* const* d_in, const int* in_sizes, int n_in,
                              void* d_out, int out_size, void* d_ws, size_t ws_size,
                              hipStream_t stream) {
    const float* x    = (const float*)d_in[0];  // enc_x [Wn*49]
    const float* wgt  = (const float*)d_in[1];  // weight [O*49]
    const float* bias = (const float*)d_in[2];  // bias [O]

    const int windows = in_sizes[0] / KK;  // 262144 (multiple of BM)
    const int ochannels = in_sizes[1] / KK;  // 512

    float* out = (float*)d_out;

    dim3 block(256);
    dim3 grid(windows / BM, ochannels / BN);
    conv_mfma_kernel<<<grid, block, 0, stream>>>(x, wgt, bias, out, windows);
}